// Round 10
// baseline (254.638 us; speedup 1.0000x reference)
//
#include <hip/hip_runtime.h>
#include <math.h>

#define BATCH   16384
#define HD      24      // LSTM hidden size
#define NOUTC   24
#define NHID    16
#define NSTEPS  47
#define NG      96
#define GRP     16      // elements per block
#define NTG     24      // thread-groups per element: w = j-slot = logit column
#define THREADS 384     // NTG * GRP, 6 waves

__device__ __forceinline__ float fast_sigmoid(float x) {
    float t = __expf(-x);
    return __builtin_amdgcn_rcpf(1.0f + t);
}
__device__ __forceinline__ float fast_tanh(float x) {
    float ax = fabsf(x);
    float t  = __expf(-2.0f * ax);
    float r  = (1.0f - t) * __builtin_amdgcn_rcpf(1.0f + t);
    return copysignf(r, x);
}

__global__ __launch_bounds__(THREADS, 6) void policy_kernel(
    const float* __restrict__ W_ih, const float* __restrict__ W_hh,
    const float* __restrict__ b_ih, const float* __restrict__ b_hh,
    const float* __restrict__ Wl,   const float* __restrict__ bl,
    const float* __restrict__ rnd,  float* __restrict__ out)
{
    __shared__ float sWihB[NG][25];          // [g][c] + bias folded; per-lane act gather
    __shared__ float sBias[NG];              // b_ih + b_hh (step 0: a == 0)
    __shared__ float sWhh4[HD][NTG][4];      // [k][w][t] = W_hh[t*24+w][k]  (float4 broadcast)
    __shared__ float sWl4[NTG][24];          // [w][k] = Wl[w][k]            (float4 broadcast)
    __shared__ float sBl[NOUTC];
    __shared__ float hbuf[2][HD][GRP];       // h double-buffered by step parity
    __shared__ float sL[NOUTC][GRP];         // logits exchange
    __shared__ float sE[NOUTC][GRP];         // exp exchange
    __shared__ float sPr[GRP][NSTEPS + 2];   // stride 49 -> bank-spread staging
    __shared__ unsigned char sAct8[GRP][NSTEPS + 2];

    const int tid = threadIdx.x;
    const int w   = tid >> 4;                // thread-group 0..23 (j-slot / logit column)
    const int e   = tid & 15;                // element within group
    const int b   = blockIdx.x * GRP + e;

    // ---- staging (once per block) ----
    for (int i = tid; i < NG * HD; i += THREADS) {
        int g = i / HD, k = i % HD;
        float bs = b_ih[g] + b_hh[g];
        sWihB[g][k] = W_ih[i] + bs;          // column gather table, bias folded
        sWhh4[k][g % 24][g / 24] = W_hh[i];  // [k][w][t]
    }
    for (int i = tid; i < NOUTC * HD; i += THREADS)
        (&sWl4[0][0])[i] = Wl[i];            // row-major copy == [w][k]
    if (tid < NG)    sBias[tid] = b_ih[tid] + b_hh[tid];
    if (tid < NOUTC) sBl[tid]   = bl[tid];
    for (int i = tid; i < 2 * HD * GRP; i += THREADS) (&hbuf[0][0][0])[i] = 0.f;
    __syncthreads();

    float c_state = 0.f;                     // own j-slot's cell state
    int act = 0;

    for (int s = 0; s < NSTEPS; ++s) {
        const int par = s & 1;
        const float r = rnd[s * BATCH + b];  // issued early, used in finish

        // ---- gates for j-slot w: a0..a3 = (i,f,g,o) ----
        float a0, a1, a2, a3;
        if (s == 0) {
            a0 = sBias[w];      a1 = sBias[24 + w];
            a2 = sBias[48 + w]; a3 = sBias[72 + w];
        } else {
            a0 = sWihB[w][act];      a1 = sWihB[24 + w][act];
            a2 = sWihB[48 + w][act]; a3 = sWihB[72 + w][act];
        }
        #pragma unroll 6
        for (int k = 0; k < HD; ++k) {
            float hk = hbuf[par][k][e];                    // 16-addr broadcast, conflict-free
            float4 wv = *(const float4*)&sWhh4[k][w][0];   // 4-addr broadcast per wave
            a0 = fmaf(hk, wv.x, a0);
            a1 = fmaf(hk, wv.y, a1);
            a2 = fmaf(hk, wv.z, a2);
            a3 = fmaf(hk, wv.w, a3);
        }

        // ---- LSTM cell for own j-slot ----
        float si = fast_sigmoid(a0);
        float sf = fast_sigmoid(a1);
        float tg = fast_tanh(a2);
        float so = fast_sigmoid(a3);
        float cj = sf * c_state + si * tg;
        c_state = cj;
        hbuf[1 - par][w][e] = so * fast_tanh(cj);
        __syncthreads();   // B: new h visible

        // ---- logit column w ----
        float l = 0.f;
        #pragma unroll
        for (int k4 = 0; k4 < 6; ++k4) {
            float4 wv = *(const float4*)&sWl4[w][k4 * 4];
            l = fmaf(hbuf[1 - par][k4 * 4 + 0][e], wv.x, l);  // fmaf(h0,w0,0) == h0*w0 exactly
            l = fmaf(hbuf[1 - par][k4 * 4 + 1][e], wv.y, l);
            l = fmaf(hbuf[1 - par][k4 * 4 + 2][e], wv.z, l);
            l = fmaf(hbuf[1 - par][k4 * 4 + 3][e], wv.w, l);
        }
        l += sBl[w];
        sL[w][e] = l;
        __syncthreads();   // C: logits visible

        // ---- masked max (redundant, cheap) + own-column exp ----
        const int  cnt = (s + 1) >> 1;
        const bool odd = (s & 1) != 0;
        float m = -INFINITY;
        #pragma unroll
        for (int n = 0; n < NOUTC; ++n) {
            bool msk = odd ? (n < cnt) : (n >= NHID);
            float vn = sL[n][e];
            m = fmaxf(m, msk ? vn : -INFINITY);
        }
        bool mskw = odd ? (w < cnt) : (w >= NHID);
        sE[w][e] = mskw ? __expf(l - m) : 0.f;
        __syncthreads();   // D: exps visible

        // ---- finish: Z + cumsum (redundant per thread; bit-identical everywhere) ----
        float Z = 0.f;
        #pragma unroll
        for (int n = 0; n < NOUTC; ++n) Z += sE[n][e];      // sequential 0..23
        const float rZ = r * Z;                              // cum(e) > r*Z == cum(e/Z) > r
        float cum = 0.f, ea = 0.f;
        int a = 0;
        bool found = false;
        #pragma unroll
        for (int n = 0; n < NOUTC; ++n) {
            float en = sE[n][e];
            cum += en;
            if (!found && cum > rZ) { found = true; a = n; ea = en; }
        }
        if (!found) { a = 0; ea = sE[0][e]; }               // unreachable safety
        float pr = ea / Z;                                   // IEEE div, mirrors reference p[act]

        if (w == 0) { sPr[e][s] = pr; sAct8[e][s] = (unsigned char)a; }
        act = a;
    }

    __syncthreads();
    // ---- coalesced write-out ----
    const int base = blockIdx.x * GRP * NSTEPS;
    for (int i = tid; i < GRP * NSTEPS; i += THREADS) {
        int rr = i / NSTEPS, ss = i - rr * NSTEPS;
        out[base + i]                          = sPr[rr][ss];
        out[(size_t)BATCH * NSTEPS + base + i] = (float)sAct8[rr][ss];
    }
}

extern "C" void kernel_launch(void* const* d_in, const int* in_sizes, int n_in,
                              void* d_out, int out_size, void* d_ws, size_t ws_size,
                              hipStream_t stream) {
    const float* W_ih = (const float*)d_in[0];
    const float* W_hh = (const float*)d_in[1];
    const float* b_ih = (const float*)d_in[2];
    const float* b_hh = (const float*)d_in[3];
    const float* Wl   = (const float*)d_in[4];
    const float* bl   = (const float*)d_in[5];
    const float* rnd  = (const float*)d_in[6];
    float* o = (float*)d_out;

    policy_kernel<<<BATCH / GRP, THREADS, 0, stream>>>(W_ih, W_hh, b_ih, b_hh, Wl, bl, rnd, o);
}

// Round 11
// 181.265 us; speedup vs baseline: 1.4048x; 1.4048x over previous
//
#include <hip/hip_runtime.h>
#include <math.h>

#define BATCH   16384
#define HD      24      // LSTM hidden size
#define NOUTC   24
#define NHID    16
#define NSTEPS  47
#define NG      96
#define GRP     32      // elements per block
#define NTG     12      // thread-groups per element
#define JPW     2       // j-slots per thread-group
#define GPW     8       // gates per thread-group
#define THREADS 384     // NTG * GRP, 6 waves; grid 512 -> 2 blocks/CU

__device__ __forceinline__ float fast_sigmoid(float x) {
    float t = __expf(-x);
    return __builtin_amdgcn_rcpf(1.0f + t);
}
__device__ __forceinline__ float fast_tanh(float x) {
    float ax = fabsf(x);
    float t  = __expf(-2.0f * ax);
    float r  = (1.0f - t) * __builtin_amdgcn_rcpf(1.0f + t);
    return copysignf(r, x);
}

__global__ __launch_bounds__(THREADS) void policy_kernel(
    const float* __restrict__ W_ih, const float* __restrict__ W_hh,
    const float* __restrict__ b_ih, const float* __restrict__ b_hh,
    const float* __restrict__ Wl,   const float* __restrict__ bl,
    const float* __restrict__ rnd,  float* __restrict__ out)
{
    __shared__ float sWihB[NG][25];          // [g][c] + bias folded (stride 25 spreads acts over banks)
    __shared__ float sBias[NG];              // b_ih + b_hh (step 0)
    __shared__ float sWhhP[HD][NTG][GPW];    // [k][w][t*2+i] : gate g = t*24 + w*2 + i
    __shared__ float sWlP[HD][NTG][JPW];     // [k][w][i] : logit col n = w*2+i
    __shared__ float sBl[NOUTC];
    __shared__ float hh[HD][GRP];            // single h buffer (reads/writes barrier-separated)
    __shared__ float sL[NOUTC][GRP];         // logits exchange
    __shared__ float sPr[GRP][NSTEPS + 2];   // stride 49 -> bank-spread staging
    __shared__ unsigned char sAct8[GRP][NSTEPS + 2];

    const int tid = threadIdx.x;
    const int w   = tid >> 5;                // thread-group 0..11
    const int e   = tid & 31;                // element within group
    const int b   = blockIdx.x * GRP + e;

    // ---- staging (once per block) ----
    for (int i = tid; i < NG * HD; i += THREADS) {
        int g = i / HD, k = i % HD;
        float bs = b_ih[g] + b_hh[g];
        sWihB[g][k] = W_ih[i] + bs;          // column gather table, bias folded
        int t = g / 24, rem = g % 24;
        sWhhP[k][rem >> 1][t * JPW + (rem & 1)] = W_hh[i];
    }
    for (int i = tid; i < NOUTC * HD; i += THREADS) {
        int n = i / HD, k = i % HD;
        sWlP[k][n >> 1][n & 1] = Wl[i];
    }
    if (tid < NG)    sBias[tid] = b_ih[tid] + b_hh[tid];
    if (tid < NOUTC) sBl[tid]   = bl[tid];
    for (int i = tid; i < HD * GRP; i += THREADS) (&hh[0][0])[i] = 0.f;
    __syncthreads();

    float cst[JPW] = {0.f, 0.f};
    float accN[GPW];                          // GEMV partial for step s (h-term); h0=0 -> exactly 0
    #pragma unroll
    for (int q = 0; q < GPW; ++q) accN[q] = 0.f;
    int act = 0;

    for (int s = 0; s < NSTEPS; ++s) {
        const float r = rnd[s * BATCH + b];   // issue early; consumed after barrier C

        // ---- complete gates: acc = GEMV-partial + (gather row with bias folded) ----
        float acc[GPW];
        if (s == 0) {
            #pragma unroll
            for (int t = 0; t < 4; ++t)
                #pragma unroll
                for (int i = 0; i < JPW; ++i)
                    acc[t * JPW + i] = accN[t * JPW + i] + sBias[t * 24 + w * JPW + i];
        } else {
            #pragma unroll
            for (int t = 0; t < 4; ++t)
                #pragma unroll
                for (int i = 0; i < JPW; ++i)
                    acc[t * JPW + i] = accN[t * JPW + i] + sWihB[t * 24 + w * JPW + i][act];
        }

        // ---- LSTM cell for own 2 j's ----
        #pragma unroll
        for (int i = 0; i < JPW; ++i) {
            float ig = acc[i], fg = acc[JPW + i], gg = acc[2 * JPW + i], og = acc[3 * JPW + i];
            float si = fast_sigmoid(ig);
            float sf = fast_sigmoid(fg);
            float so = fast_sigmoid(og);
            float tg = fast_tanh(gg);
            float cj = sf * cst[i] + si * tg;
            cst[i] = cj;
            hh[w * JPW + i][e] = so * fast_tanh(cj);
        }
        __syncthreads();   // B: new h visible

        // ---- merged k-loop: logits(s) + gates-GEMV(s+1), same h ----
        float l0 = 0.f, l1 = 0.f;
        #pragma unroll
        for (int q = 0; q < GPW; ++q) accN[q] = 0.f;
        #pragma unroll 6
        for (int k = 0; k < HD; ++k) {
            float hk = hh[k][e];                           // bank e -> conflict-free
            const float* wp = &sWhhP[k][w][0];             // wave: 2 groups -> 2 b128 broadcasts
            float4 w0 = *(const float4*)&wp[0];
            float4 w1 = *(const float4*)&wp[4];
            float2 lv = *(const float2*)&sWlP[k][w][0];
            accN[0] = fmaf(hk, w0.x, accN[0]);
            accN[1] = fmaf(hk, w0.y, accN[1]);
            accN[2] = fmaf(hk, w0.z, accN[2]);
            accN[3] = fmaf(hk, w0.w, accN[3]);
            accN[4] = fmaf(hk, w1.x, accN[4]);
            accN[5] = fmaf(hk, w1.y, accN[5]);
            accN[6] = fmaf(hk, w1.z, accN[6]);
            accN[7] = fmaf(hk, w1.w, accN[7]);
            l0 = fmaf(hk, lv.x, l0);
            l1 = fmaf(hk, lv.y, l1);
        }
        sL[w * JPW + 0][e] = l0 + sBl[w * JPW + 0];
        sL[w * JPW + 1][e] = l1 + sBl[w * JPW + 1];
        __syncthreads();   // C: logits visible

        // ---- redundant in-register finish (mask range is wave-uniform) ----
        const int  cnt = (s + 1) >> 1;
        const bool odd = (s & 1) != 0;
        float v[NOUTC];
        #pragma unroll
        for (int n = 0; n < NOUTC; ++n) v[n] = sL[n][e];
        float Z = 0.f, cum = 0.f, ea = 0.f, m = -INFINITY;
        int a = 0;
        bool found = false;
        if (odd) {
            #pragma unroll
            for (int n = 0; n < NOUTC; ++n) m = fmaxf(m, (n < cnt) ? v[n] : -INFINITY);
            #pragma unroll
            for (int n = 0; n < NOUTC; ++n) v[n] = (n < cnt) ? __expf(v[n] - m) : 0.f;
            #pragma unroll
            for (int n = 0; n < NOUTC; ++n) Z += v[n];          // ascending; zeros exact
            const float rZ = r * Z;
            #pragma unroll
            for (int n = 0; n < NOUTC; ++n) {
                cum += v[n];
                if (!found && cum > rZ) { found = true; a = n; ea = v[n]; }
            }
            if (!found) { a = 0; ea = v[0]; }                   // n=0 always in mask (cnt>=1)
        } else {
            #pragma unroll
            for (int n = NHID; n < NOUTC; ++n) m = fmaxf(m, v[n]);
            #pragma unroll
            for (int n = NHID; n < NOUTC; ++n) v[n] = __expf(v[n] - m);
            #pragma unroll
            for (int n = NHID; n < NOUTC; ++n) Z += v[n];       // masked-out are exact zeros
            const float rZ = r * Z;
            #pragma unroll
            for (int n = NHID; n < NOUTC; ++n) {
                cum += v[n];
                if (!found && cum > rZ) { found = true; a = n; ea = v[n]; }
            }
            if (!found) { a = 0; ea = 0.f; }                    // ref: p[0]=0 on even steps
        }
        float pr = ea / Z;                                      // IEEE div, mirrors reference

        if (w == 0) { sPr[e][s] = pr; sAct8[e][s] = (unsigned char)a; }
        act = a;
    }

    __syncthreads();
    // ---- coalesced write-out ----
    const int base = blockIdx.x * GRP * NSTEPS;
    for (int i = tid; i < GRP * NSTEPS; i += THREADS) {
        int rr = i / NSTEPS, ss = i - rr * NSTEPS;
        out[base + i]                          = sPr[rr][ss];
        out[(size_t)BATCH * NSTEPS + base + i] = (float)sAct8[rr][ss];
    }
}

extern "C" void kernel_launch(void* const* d_in, const int* in_sizes, int n_in,
                              void* d_out, int out_size, void* d_ws, size_t ws_size,
                              hipStream_t stream) {
    const float* W_ih = (const float*)d_in[0];
    const float* W_hh = (const float*)d_in[1];
    const float* b_ih = (const float*)d_in[2];
    const float* b_hh = (const float*)d_in[3];
    const float* Wl   = (const float*)d_in[4];
    const float* bl   = (const float*)d_in[5];
    const float* rnd  = (const float*)d_in[6];
    float* o = (float*)d_out;

    policy_kernel<<<BATCH / GRP, THREADS, 0, stream>>>(W_ih, W_hh, b_ih, b_hh, Wl, bl, rnd, o);
}

// Round 12
// 170.298 us; speedup vs baseline: 1.4953x; 1.0644x over previous
//
#include <hip/hip_runtime.h>
#include <math.h>

#define BATCH   16384
#define HD      24      // LSTM hidden size
#define NOUTC   24
#define NHID    16
#define NSTEPS  47
#define NG      96
#define GRP     16      // elements per block
#define NTG     12      // thread-groups per element
#define JPW     2       // j-slots per thread-group
#define GPW     8       // gates per thread-group
#define THREADS 192     // NTG * GRP, 3 waves; grid 1024 -> 4 blocks/CU

__device__ __forceinline__ float fast_sigmoid(float x) {
    float t = __expf(-x);
    return __builtin_amdgcn_rcpf(1.0f + t);
}
__device__ __forceinline__ float fast_tanh(float x) {
    float ax = fabsf(x);
    float t  = __expf(-2.0f * ax);
    float r  = (1.0f - t) * __builtin_amdgcn_rcpf(1.0f + t);
    return copysignf(r, x);
}

__global__ __launch_bounds__(THREADS) void policy_kernel(
    const float* __restrict__ W_ih, const float* __restrict__ W_hh,
    const float* __restrict__ b_ih, const float* __restrict__ b_hh,
    const float* __restrict__ Wl,   const float* __restrict__ bl,
    const float* __restrict__ rnd,  float* __restrict__ out)
{
    __shared__ float sWihB[NG][25];          // [g][c] + bias folded (stride 25 spreads acts over banks)
    __shared__ float sBias[NG];              // b_ih + b_hh (step 0)
    __shared__ float sWhhP[HD][NTG][GPW];    // [k][w][t*2+i] : gate g = t*24 + w*2 + i
    __shared__ float sWlP[HD][NTG][JPW];     // [k][w][i] : logit col n = w*2+i
    __shared__ float sBl[NOUTC];
    __shared__ float hh[HD][GRP];            // single h buffer (reads/writes barrier-separated)
    __shared__ float sLt[GRP][28];           // transposed logits exchange (28: float4-aligned, 2-way-free banks)
    __shared__ float sPr[GRP][NSTEPS + 2];   // stride 49 -> bank-spread staging
    __shared__ unsigned char sAct8[GRP][NSTEPS + 2];

    const int tid = threadIdx.x;
    const int w   = tid >> 4;                // thread-group 0..11
    const int e   = tid & 15;                // element within group
    const int b   = blockIdx.x * GRP + e;

    // ---- staging (once per block) ----
    for (int i = tid; i < NG * HD; i += THREADS) {
        int g = i / HD, k = i % HD;
        float bs = b_ih[g] + b_hh[g];
        sWihB[g][k] = W_ih[i] + bs;          // column gather table, bias folded
        int t = g / 24, rem = g % 24;
        sWhhP[k][rem >> 1][t * JPW + (rem & 1)] = W_hh[i];
    }
    for (int i = tid; i < NOUTC * HD; i += THREADS) {
        int n = i / HD, k = i % HD;
        sWlP[k][n >> 1][n & 1] = Wl[i];
    }
    if (tid < NG)    sBias[tid] = b_ih[tid] + b_hh[tid];
    if (tid < NOUTC) sBl[tid]   = bl[tid];
    for (int i = tid; i < HD * GRP; i += THREADS) (&hh[0][0])[i] = 0.f;
    __syncthreads();

    float cst[JPW] = {0.f, 0.f};
    float accN[GPW];                          // GEMV partial for step s (h-term); h0=0 -> exactly 0
    #pragma unroll
    for (int q = 0; q < GPW; ++q) accN[q] = 0.f;
    int act = 0;

    for (int s = 0; s < NSTEPS; ++s) {
        const float r = rnd[s * BATCH + b];   // issue early; consumed after barrier C

        // ---- complete gates: acc = GEMV-partial + (gather row with bias folded) ----
        float acc[GPW];
        if (s == 0) {
            #pragma unroll
            for (int t = 0; t < 4; ++t)
                #pragma unroll
                for (int i = 0; i < JPW; ++i)
                    acc[t * JPW + i] = accN[t * JPW + i] + sBias[t * 24 + w * JPW + i];
        } else {
            #pragma unroll
            for (int t = 0; t < 4; ++t)
                #pragma unroll
                for (int i = 0; i < JPW; ++i)
                    acc[t * JPW + i] = accN[t * JPW + i] + sWihB[t * 24 + w * JPW + i][act];
        }

        // ---- LSTM cell for own 2 j's ----
        #pragma unroll
        for (int i = 0; i < JPW; ++i) {
            float ig = acc[i], fg = acc[JPW + i], gg = acc[2 * JPW + i], og = acc[3 * JPW + i];
            float si = fast_sigmoid(ig);
            float sf = fast_sigmoid(fg);
            float so = fast_sigmoid(og);
            float tg = fast_tanh(gg);
            float cj = sf * cst[i] + si * tg;
            cst[i] = cj;
            hh[w * JPW + i][e] = so * fast_tanh(cj);
        }
        __syncthreads();   // B: new h visible

        // ---- merged k-loop: logits(s) + gates-GEMV(s+1), same h ----
        float l0 = 0.f, l1 = 0.f;
        #pragma unroll
        for (int q = 0; q < GPW; ++q) accN[q] = 0.f;
        #pragma unroll 6
        for (int k = 0; k < HD; ++k) {
            float hk = hh[k][e];                           // 16 banks, 4-way broadcast (free)
            const float* wp = &sWhhP[k][w][0];             // wave's 4 groups -> disjoint bank quads
            float4 w0 = *(const float4*)&wp[0];
            float4 w1 = *(const float4*)&wp[4];
            float2 lv = *(const float2*)&sWlP[k][w][0];
            accN[0] = fmaf(hk, w0.x, accN[0]);
            accN[1] = fmaf(hk, w0.y, accN[1]);
            accN[2] = fmaf(hk, w0.z, accN[2]);
            accN[3] = fmaf(hk, w0.w, accN[3]);
            accN[4] = fmaf(hk, w1.x, accN[4]);
            accN[5] = fmaf(hk, w1.y, accN[5]);
            accN[6] = fmaf(hk, w1.z, accN[6]);
            accN[7] = fmaf(hk, w1.w, accN[7]);
            l0 = fmaf(hk, lv.x, l0);
            l1 = fmaf(hk, lv.y, l1);
        }
        sLt[e][w * JPW + 0] = l0 + sBl[w * JPW + 0];
        sLt[e][w * JPW + 1] = l1 + sBl[w * JPW + 1];
        __syncthreads();   // C: logits visible

        // ---- redundant in-register finish (vectorized logit loads) ----
        const int  cnt = (s + 1) >> 1;
        const bool odd = (s & 1) != 0;
        float v[NOUTC];
        #pragma unroll
        for (int n4 = 0; n4 < 6; ++n4) {
            float4 vv = *(const float4*)&sLt[e][n4 * 4];   // b128, 2-way bank alias (free)
            v[n4 * 4 + 0] = vv.x; v[n4 * 4 + 1] = vv.y;
            v[n4 * 4 + 2] = vv.z; v[n4 * 4 + 3] = vv.w;
        }
        float Z = 0.f, cum = 0.f, ea = 0.f, m = -INFINITY;
        int a = 0;
        bool found = false;
        if (odd) {
            #pragma unroll
            for (int n = 0; n < NOUTC; ++n) m = fmaxf(m, (n < cnt) ? v[n] : -INFINITY);
            #pragma unroll
            for (int n = 0; n < NOUTC; ++n) v[n] = (n < cnt) ? __expf(v[n] - m) : 0.f;
            #pragma unroll
            for (int n = 0; n < NOUTC; ++n) Z += v[n];          // ascending; zeros exact
            const float rZ = r * Z;
            #pragma unroll
            for (int n = 0; n < NOUTC; ++n) {
                cum += v[n];
                if (!found && cum > rZ) { found = true; a = n; ea = v[n]; }
            }
            if (!found) { a = 0; ea = v[0]; }                   // n=0 always in mask (cnt>=1)
        } else {
            #pragma unroll
            for (int n = NHID; n < NOUTC; ++n) m = fmaxf(m, v[n]);
            #pragma unroll
            for (int n = NHID; n < NOUTC; ++n) v[n] = __expf(v[n] - m);
            #pragma unroll
            for (int n = NHID; n < NOUTC; ++n) Z += v[n];       // masked-out are exact zeros
            const float rZ = r * Z;
            #pragma unroll
            for (int n = NHID; n < NOUTC; ++n) {
                cum += v[n];
                if (!found && cum > rZ) { found = true; a = n; ea = v[n]; }
            }
            if (!found) { a = 0; ea = 0.f; }                    // ref: p[0]=0 on even steps
        }
        float pr = ea / Z;                                      // IEEE div, mirrors reference

        if (w == 0) { sPr[e][s] = pr; sAct8[e][s] = (unsigned char)a; }
        act = a;
    }

    __syncthreads();
    // ---- coalesced write-out ----
    const int base = blockIdx.x * GRP * NSTEPS;
    for (int i = tid; i < GRP * NSTEPS; i += THREADS) {
        int rr = i / NSTEPS, ss = i - rr * NSTEPS;
        out[base + i]                          = sPr[rr][ss];
        out[(size_t)BATCH * NSTEPS + base + i] = (float)sAct8[rr][ss];
    }
}

extern "C" void kernel_launch(void* const* d_in, const int* in_sizes, int n_in,
                              void* d_out, int out_size, void* d_ws, size_t ws_size,
                              hipStream_t stream) {
    const float* W_ih = (const float*)d_in[0];
    const float* W_hh = (const float*)d_in[1];
    const float* b_ih = (const float*)d_in[2];
    const float* b_hh = (const float*)d_in[3];
    const float* Wl   = (const float*)d_in[4];
    const float* bl   = (const float*)d_in[5];
    const float* rnd  = (const float*)d_in[6];
    float* o = (float*)d_out;

    policy_kernel<<<BATCH / GRP, THREADS, 0, stream>>>(W_ih, W_hh, b_ih, b_hh, Wl, bl, rnd, o);
}